// Round 1
// baseline (216.824 us; speedup 1.0000x reference)
//
#include <hip/hip_runtime.h>

typedef __attribute__((ext_vector_type(8))) __bf16 bf16x8;
typedef __attribute__((ext_vector_type(4))) float f32x4;
typedef unsigned short u16;
typedef unsigned int u32;

#define VMCNT(n) asm volatile("s_waitcnt vmcnt(" #n ")" ::: "memory")

__device__ __forceinline__ u16 f2bf(float f) {
  union { float f; u32 u; } v; v.f = f;
  u32 r = v.u + 0x7FFFu + ((v.u >> 16) & 1u);
  return (u16)(r >> 16);
}
__device__ __forceinline__ float fexp2(float x) {  // 2^x via v_exp_f32
  float r; asm("v_exp_f32 %0, %1" : "=v"(r) : "v"(x)); return r;
}

// ---------------- cast x fp32 -> bf16 (4 elems/thread) ----------------
__global__ __launch_bounds__(256) void cast_x_kernel(const float* __restrict__ x,
                                                     u16* __restrict__ xb, int n4) {
  int i = blockIdx.x * 256 + threadIdx.x;
  if (i >= n4) return;
  float4 v = reinterpret_cast<const float4*>(x)[i];
  ushort4 o;
  o.x = f2bf(v.x); o.y = f2bf(v.y); o.z = f2bf(v.z); o.w = f2bf(v.w);
  reinterpret_cast<ushort4*>(xb)[i] = o;
}

// ------- transpose weights: Wt[u][d] = W[d][u], fp32 -> bf16 ----------
__global__ __launch_bounds__(1024) void transpose_w_kernel(const float* __restrict__ Wq,
                                                           const float* __restrict__ Wk,
                                                           const float* __restrict__ Wv,
                                                           u16* __restrict__ Wt) {
  const float* src = blockIdx.z == 0 ? Wq : (blockIdx.z == 1 ? Wk : Wv);
  u16* dst = Wt + (size_t)blockIdx.z * 512 * 512;
  __shared__ float tile[32][33];
  int u0 = blockIdx.x * 32, d0 = blockIdx.y * 32;
  tile[threadIdx.y][threadIdx.x] = src[(d0 + threadIdx.y) * 512 + u0 + threadIdx.x];
  __syncthreads();
  dst[(u0 + threadIdx.y) * 512 + d0 + threadIdx.x] = f2bf(tile[threadIdx.x][threadIdx.y]);
}

// ---------------- QKV projection: 128x128 tile, ring-3 counted-vmcnt ----
__global__ __launch_bounds__(256) void qkv_kernel(const u16* __restrict__ Xb,
                                                  const u16* __restrict__ Wt3,
                                                  u16* __restrict__ Q, u16* __restrict__ K,
                                                  u16* __restrict__ Vt) {
  __shared__ u16 As[3][128 * 32], Bs[3][128 * 32];
  const int bm = blockIdx.y * 128;
  const int bn = blockIdx.x * 128;
  const int z = blockIdx.z;
  const u16* A = Xb + (size_t)bm * 512;
  const u16* Bt = Wt3 + (size_t)z * 512 * 512 + (size_t)bn * 512;

  const int t = threadIdx.x;
  const int lane = t & 63;
  const int w = t >> 6;
  const int wr = w >> 1, wc = w & 1;
  const int la = lane & 15;
  const int q = lane >> 4;
  f32x4 acc[4][4] = {};

  auto stage = [&](int buf, int kt) {
    const int k0 = kt * 32;
#pragma unroll
    for (int it = 0; it < 2; ++it) {    // A: 128 rows -> 512 chunks
      int c = it * 256 + t, row = c >> 2;
      int col = ((c & 3) ^ ((row >> 1) & 3)) << 3;
      __builtin_amdgcn_global_load_lds(
          (const __attribute__((address_space(1))) void*)(A + (size_t)row * 512 + k0 + col),
          (__attribute__((address_space(3))) void*)(&As[buf][c * 8]), 16, 0, 0);
    }
#pragma unroll
    for (int it = 0; it < 2; ++it) {    // B: 128 rows -> 512 chunks
      int c = it * 256 + t, row = c >> 2;
      int col = ((c & 3) ^ ((row >> 1) & 3)) << 3;
      __builtin_amdgcn_global_load_lds(
          (const __attribute__((address_space(1))) void*)(Bt + (size_t)row * 512 + k0 + col),
          (__attribute__((address_space(3))) void*)(&Bs[buf][c * 8]), 16, 0, 0);
    }
  };

  auto body = [&](int buf) {
    bf16x8 a[4], b[4];
#pragma unroll
    for (int i = 0; i < 4; ++i) {
      int row = wr * 64 + i * 16 + la;
      a[i] = *reinterpret_cast<const bf16x8*>(&As[buf][row * 32 + ((q ^ ((row >> 1) & 3)) << 3)]);
    }
#pragma unroll
    for (int j = 0; j < 4; ++j) {
      int row = wc * 64 + j * 16 + la;
      b[j] = *reinterpret_cast<const bf16x8*>(&Bs[buf][row * 32 + ((q ^ ((row >> 1) & 3)) << 3)]);
    }
    __builtin_amdgcn_s_setprio(1);
#pragma unroll
    for (int i = 0; i < 4; ++i)
#pragma unroll
      for (int j = 0; j < 4; ++j)
        acc[i][j] = __builtin_amdgcn_mfma_f32_16x16x32_bf16(a[i], b[j], acc[i][j], 0, 0, 0);
    __builtin_amdgcn_s_setprio(0);
  };

  stage(0, 0); stage(1, 1);             // 8 loads/thread in flight
  int cb = 0, sb = 2;
  for (int kt = 0; kt < 14; ++kt) {
    VMCNT(4);                           // tile kt landed; kt+1 flying
    __builtin_amdgcn_s_barrier();       // all waves' kt landed; buf sb free
    stage(sb, kt + 2);
    body(cb);
    cb = (cb == 2) ? 0 : cb + 1;
    sb = (sb == 2) ? 0 : sb + 1;
  }
  VMCNT(4); __builtin_amdgcn_s_barrier(); body(2);   // kt=14 -> buf 14%3=2
  VMCNT(0); __builtin_amdgcn_s_barrier(); body(0);   // kt=15 -> buf 0

  const int r0 = q * 4, cn = lane & 15;
  if (z < 2) {
    u16* out = (z == 0) ? Q : K;
#pragma unroll
    for (int i = 0; i < 4; ++i)
#pragma unroll
      for (int j = 0; j < 4; ++j)
#pragma unroll
        for (int r = 0; r < 4; ++r) {
          int m = bm + 64 * wr + 16 * i + r0 + r;
          int n = bn + 64 * wc + 16 * j + cn;
          out[(size_t)m * 512 + n] = f2bf(acc[i][j][r]);
        }
  } else {
#pragma unroll
    for (int i = 0; i < 4; ++i)
#pragma unroll
      for (int j = 0; j < 4; ++j)
#pragma unroll
        for (int r = 0; r < 4; ++r) {
          int m = bm + 64 * wr + 16 * i + r0 + r;
          int u = bn + 64 * wc + 16 * j + cn;
          int b = m >> 11, s = m & 2047;
          Vt[((size_t)b * 512 + u) * 2048 + s] = f2bf(acc[i][j][r]);
        }
  }
}

// ------ P = exp(Q K^T / sqrt(512)) -> bf16: 256x256, ring-4 (round-14) ------
__global__ __launch_bounds__(512) void scores8_kernel(const u16* __restrict__ Q,
                                                      const u16* __restrict__ K,
                                                      u16* __restrict__ S) {
  __shared__ u16 ring[4][2][256 * 32];  // [buf][A=0/B=1][256 rows][32 k]
  const int bb = blockIdx.x;            // batch -> XCD
  const int bm = blockIdx.y * 256;
  const int bn = blockIdx.z * 256;
  const u16* Aq = Q + (size_t)(bb * 2048 + bm) * 512;
  const u16* Bk = K + (size_t)(bb * 2048 + bn) * 512;

  const int t = threadIdx.x;
  const int lane = t & 63;
  const int wid = t >> 6;
  const int wm = wid >> 2, wn = wid & 3;
  const int la = lane & 15;
  const int q = lane >> 4;              // k-slot 0..3 (8 elems each)

  f32x4 acc[8][4] = {};

  auto stage = [&](int kt) {
    const int r = kt & 3;
    const int koff = kt * 32;
#pragma unroll
    for (int half = 0; half < 2; ++half) {
      int c = half * 512 + t;
      int row = c >> 2;
      int col = ((c & 3) ^ ((row >> 1) & 3)) << 3;   // inverse swizzle on source
      __builtin_amdgcn_global_load_lds(
          (const __attribute__((address_space(1))) void*)(Aq + (size_t)row * 512 + koff + col),
          (__attribute__((address_space(3))) void*)(&ring[r][0][c * 8]), 16, 0, 0);
      __builtin_amdgcn_global_load_lds(
          (const __attribute__((address_space(1))) void*)(Bk + (size_t)row * 512 + koff + col),
          (__attribute__((address_space(3))) void*)(&ring[r][1][c * 8]), 16, 0, 0);
    }
  };

  auto body = [&](int kt) {
    const int r = kt & 3;
    const u16* At = ring[r][0];
    const u16* Bt = ring[r][1];
    bf16x8 bfr[4], afr[8];
#pragma unroll
    for (int j = 0; j < 4; ++j) {
      int row = wn * 64 + j * 16 + la;
      bfr[j] = *reinterpret_cast<const bf16x8*>(Bt + row * 32 + ((q ^ ((row >> 1) & 3)) << 3));
    }
#pragma unroll
    for (int i = 0; i < 8; ++i) {
      int row = wm * 128 + i * 16 + la;
      afr[i] = *reinterpret_cast<const bf16x8*>(At + row * 32 + ((q ^ ((row >> 1) & 3)) << 3));
    }
    __builtin_amdgcn_s_setprio(1);
#pragma unroll
    for (int i = 0; i < 8; ++i)
#pragma unroll
      for (int j = 0; j < 4; ++j)
        acc[i][j] = __builtin_amdgcn_mfma_f32_16x16x32_bf16(afr[i], bfr[j], acc[i][j], 0, 0, 0);
    __builtin_amdgcn_s_setprio(0);
  };

  stage(0); stage(1); stage(2);         // 12 loads/thread in flight
  for (int kt = 0; kt < 13; ++kt) {
    VMCNT(8);                           // kt's 4 loads landed; kt+1/kt+2 fly
    __builtin_amdgcn_s_barrier();       // all waves' kt landed; buf[(kt+3)&3] free
    stage(kt + 3);
    body(kt);
  }
  VMCNT(8); __builtin_amdgcn_s_barrier(); body(13);
  VMCNT(4); __builtin_amdgcn_s_barrier(); body(14);
  VMCNT(0); __builtin_amdgcn_s_barrier(); body(15);

  u16* C = S + (size_t)bb * 2048 * 2048;
  const float scale = 0.06375872127f;   // log2(e)/sqrt(512)
  const int r0h = q * 4;
#pragma unroll
  for (int i = 0; i < 8; ++i)
#pragma unroll
    for (int j = 0; j < 4; ++j)
#pragma unroll
      for (int r = 0; r < 4; ++r) {
        int m = bm + wm * 128 + i * 16 + r0h + r;
        int n = bn + wn * 64 + j * 16 + la;
        C[(size_t)m * 2048 + n] = f2bf(fexp2(acc[i][j][r] * scale));
      }
}

// ---- out = (P * V) / rowsum(P): 128x128 tile, DIRECT global->reg ----
// S (64 MB, just written) and Vt (16.8 MB) are L2/L3-resident; LDS staging
// was pure overhead (barrier drain x64 K-steps at only 2 waves/SIMD ->
// MfmaUtil 22%). Direct per-lane MFMA-fragment loads have the SAME global
// gather pattern as the old stage() (16 rows x 64B per wave-instr), so no
// coalescing is lost. 4-deep static register ring (all indices
// compile-time), no barriers in the K-loop: waves slip freely, compute-to-
// load distance = 3 MFMA phases (~48 MFMA) covers ~200cy L2 latency.
// __launch_bounds__(256,2) caps VGPR at 256 (est ~230: 64 acc + 128 frag).
__global__ __launch_bounds__(256, 2) void pv_kernel(const u16* __restrict__ S,
                                                    const u16* __restrict__ Vt,
                                                    float* __restrict__ out) {
  __shared__ float larr[128];
  const int id = blockIdx.x;
  const int b = id & 7;                   // batch == XCD
  const int local = id >> 3;              // 0..63
  const int bn = (local & 3) * 128;       // u cols
  const int bm = (local >> 2) * 128;      // q rows

  const int t = threadIdx.x;
  const int lane = t & 63;
  const int w = t >> 6;
  const int wr = w >> 1, wc = w & 1;
  const int la = lane & 15;
  const int q = lane >> 4;

  // A-frag: lane holds P[bm + wr*64 + i*16 + la][kt*32 + q*8 + e]
  const u16* Abase = S + (size_t)(b * 2048 + bm + wr * 64 + la) * 2048 + q * 8;
  // B-frag: lane holds Vt-row (bn + wc*64 + j*16 + la), k offset kt*32 + q*8
  const u16* Bbase = Vt + (size_t)(b * 512 + bn + wc * 64 + la) * 2048 + q * 8;

  f32x4 acc[4][4] = {};
  float lacc[4] = {0.f, 0.f, 0.f, 0.f};

  bf16x8 af[4][4], bf[4][4];            // [ring buf][frag] — static indices only

  auto lda = [&](bf16x8 (&a)[4], bf16x8 (&bb)[4], int kt) {
#pragma unroll
    for (int i = 0; i < 4; ++i)
      a[i] = *reinterpret_cast<const bf16x8*>(Abase + (size_t)i * 16 * 2048 + kt * 32);
#pragma unroll
    for (int j = 0; j < 4; ++j)
      bb[j] = *reinterpret_cast<const bf16x8*>(Bbase + (size_t)j * 16 * 2048 + kt * 32);
  };

  auto body = [&](bf16x8 (&a)[4], bf16x8 (&bb)[4]) {
    if (wc == 0) {                      // count each P element exactly once
#pragma unroll
      for (int i = 0; i < 4; ++i) {
        float ls = 0.f;
#pragma unroll
        for (int e = 0; e < 8; ++e) ls += (float)a[i][e];
        lacc[i] += ls;
      }
    }
    __builtin_amdgcn_s_setprio(1);
#pragma unroll
    for (int i = 0; i < 4; ++i)
#pragma unroll
      for (int j = 0; j < 4; ++j)
        acc[i][j] = __builtin_amdgcn_mfma_f32_16x16x32_bf16(a[i], bb[j], acc[i][j], 0, 0, 0);
    __builtin_amdgcn_s_setprio(0);
  };

  lda(af[0], bf[0], 0);
  lda(af[1], bf[1], 1);
  lda(af[2], bf[2], 2);
  lda(af[3], bf[3], 3);
  for (int it = 0; it < 15; ++it) {     // computes kt=0..59, loads kt=4..63
    const int kt = it * 4;
    body(af[0], bf[0]); lda(af[0], bf[0], kt + 4);
    body(af[1], bf[1]); lda(af[1], bf[1], kt + 5);
    body(af[2], bf[2]); lda(af[2], bf[2], kt + 6);
    body(af[3], bf[3]); lda(af[3], bf[3], kt + 7);
  }
  body(af[0], bf[0]);                   // kt=60
  body(af[1], bf[1]);                   // kt=61
  body(af[2], bf[2]);                   // kt=62
  body(af[3], bf[3]);                   // kt=63

  // ---- epilogue: reduce row partials over q-lanes, normalize, store ---
  float l[4];
#pragma unroll
  for (int i = 0; i < 4; ++i) {
    l[i] = lacc[i];
    l[i] += __shfl_xor(l[i], 16);
    l[i] += __shfl_xor(l[i], 32);       // sum across 4 q-lanes (la preserved)
  }
  if (wc == 0 && q == 0) {              // one writer per row: 2 wr x 16 la x 4 i
#pragma unroll
    for (int i = 0; i < 4; ++i) larr[wr * 64 + i * 16 + la] = l[i];
  }
  __syncthreads();

  float* C = out + ((size_t)b * 2048 + bm) * 512;
  const int r0 = q * 4, cn = lane & 15;
  float inv[4][4];
#pragma unroll
  for (int i = 0; i < 4; ++i)
#pragma unroll
    for (int r = 0; r < 4; ++r)
      inv[i][r] = 1.0f / larr[wr * 64 + i * 16 + r0 + r];
#pragma unroll
  for (int i = 0; i < 4; ++i)
#pragma unroll
    for (int j = 0; j < 4; ++j)
#pragma unroll
      for (int r = 0; r < 4; ++r) {
        int m = 64 * wr + 16 * i + r0 + r;
        int n = bn + 64 * wc + 16 * j + cn;
        C[(size_t)m * 512 + n] = acc[i][j][r] * inv[i][r];
      }
}

extern "C" void kernel_launch(void* const* d_in, const int* in_sizes, int n_in,
                              void* d_out, int out_size, void* d_ws, size_t ws_size,
                              hipStream_t stream) {
  const float* x  = (const float*)d_in[0];
  const float* Wq = (const float*)d_in[1];
  const float* Wk = (const float*)d_in[2];
  const float* Wv = (const float*)d_in[3];
  float* out = (float*)d_out;

  // ws layout: Xb bf16[16384][512] | Wt bf16[3][512][512] | Q | K | Vt | S bf16[8][2048][2048]
  char* p = (char*)d_ws;
  u16* Xb = (u16*)p;            p += (size_t)16384 * 512 * 2;
  u16* Wt = (u16*)p;            p += (size_t)3 * 512 * 512 * 2;
  u16* Q  = (u16*)p;            p += (size_t)16384 * 512 * 2;
  u16* K  = (u16*)p;            p += (size_t)16384 * 512 * 2;
  u16* Vt = (u16*)p;            p += (size_t)16384 * 512 * 2;
  u16* S  = (u16*)p;

  cast_x_kernel<<<dim3(8192), dim3(256), 0, stream>>>(x, Xb, 16384 * 512 / 4);
  transpose_w_kernel<<<dim3(16, 16, 3), dim3(32, 32), 0, stream>>>(Wq, Wk, Wv, Wt);
  qkv_kernel<<<dim3(4, 128, 3), dim3(256), 0, stream>>>(Xb, Wt, Q, K, Vt);
  scores8_kernel<<<dim3(8, 8, 8), dim3(512), 0, stream>>>(Q, K, S);
  pv_kernel<<<dim3(512), dim3(256), 0, stream>>>(S, Vt, out);
}

// Round 2
// 153.813 us; speedup vs baseline: 1.4097x; 1.4097x over previous
//
#include <hip/hip_runtime.h>

typedef __attribute__((ext_vector_type(8))) __bf16 bf16x8;
typedef __attribute__((ext_vector_type(4))) float f32x4;
typedef unsigned short u16;
typedef unsigned int u32;

#define VMCNT(n) asm volatile("s_waitcnt vmcnt(" #n ")" ::: "memory")

__device__ __forceinline__ u16 f2bf(float f) {
  union { float f; u32 u; } v; v.f = f;
  u32 r = v.u + 0x7FFFu + ((v.u >> 16) & 1u);
  return (u16)(r >> 16);
}
__device__ __forceinline__ float fexp2(float x) {  // 2^x via v_exp_f32
  float r; asm("v_exp_f32 %0, %1" : "=v"(r) : "v"(x)); return r;
}

// ---------------- cast x fp32 -> bf16 (4 elems/thread) ----------------
__global__ __launch_bounds__(256) void cast_x_kernel(const float* __restrict__ x,
                                                     u16* __restrict__ xb, int n4) {
  int i = blockIdx.x * 256 + threadIdx.x;
  if (i >= n4) return;
  float4 v = reinterpret_cast<const float4*>(x)[i];
  ushort4 o;
  o.x = f2bf(v.x); o.y = f2bf(v.y); o.z = f2bf(v.z); o.w = f2bf(v.w);
  reinterpret_cast<ushort4*>(xb)[i] = o;
}

// ------- transpose weights: Wt[u][d] = W[d][u], fp32 -> bf16 ----------
__global__ __launch_bounds__(1024) void transpose_w_kernel(const float* __restrict__ Wq,
                                                           const float* __restrict__ Wk,
                                                           const float* __restrict__ Wv,
                                                           u16* __restrict__ Wt) {
  const float* src = blockIdx.z == 0 ? Wq : (blockIdx.z == 1 ? Wk : Wv);
  u16* dst = Wt + (size_t)blockIdx.z * 512 * 512;
  __shared__ float tile[32][33];
  int u0 = blockIdx.x * 32, d0 = blockIdx.y * 32;
  tile[threadIdx.y][threadIdx.x] = src[(d0 + threadIdx.y) * 512 + u0 + threadIdx.x];
  __syncthreads();
  dst[(u0 + threadIdx.y) * 512 + d0 + threadIdx.x] = f2bf(tile[threadIdx.x][threadIdx.y]);
}

// ---------------- QKV projection: 128x128 tile, ring-3 counted-vmcnt ----
__global__ __launch_bounds__(256) void qkv_kernel(const u16* __restrict__ Xb,
                                                  const u16* __restrict__ Wt3,
                                                  u16* __restrict__ Q, u16* __restrict__ K,
                                                  u16* __restrict__ Vt) {
  __shared__ u16 As[3][128 * 32], Bs[3][128 * 32];
  const int bm = blockIdx.y * 128;
  const int bn = blockIdx.x * 128;
  const int z = blockIdx.z;
  const u16* A = Xb + (size_t)bm * 512;
  const u16* Bt = Wt3 + (size_t)z * 512 * 512 + (size_t)bn * 512;

  const int t = threadIdx.x;
  const int lane = t & 63;
  const int w = t >> 6;
  const int wr = w >> 1, wc = w & 1;
  const int la = lane & 15;
  const int q = lane >> 4;
  f32x4 acc[4][4] = {};

  auto stage = [&](int buf, int kt) {
    const int k0 = kt * 32;
#pragma unroll
    for (int it = 0; it < 2; ++it) {    // A: 128 rows -> 512 chunks
      int c = it * 256 + t, row = c >> 2;
      int col = ((c & 3) ^ ((row >> 1) & 3)) << 3;
      __builtin_amdgcn_global_load_lds(
          (const __attribute__((address_space(1))) void*)(A + (size_t)row * 512 + k0 + col),
          (__attribute__((address_space(3))) void*)(&As[buf][c * 8]), 16, 0, 0);
    }
#pragma unroll
    for (int it = 0; it < 2; ++it) {    // B: 128 rows -> 512 chunks
      int c = it * 256 + t, row = c >> 2;
      int col = ((c & 3) ^ ((row >> 1) & 3)) << 3;
      __builtin_amdgcn_global_load_lds(
          (const __attribute__((address_space(1))) void*)(Bt + (size_t)row * 512 + k0 + col),
          (__attribute__((address_space(3))) void*)(&Bs[buf][c * 8]), 16, 0, 0);
    }
  };

  auto body = [&](int buf) {
    bf16x8 a[4], b[4];
#pragma unroll
    for (int i = 0; i < 4; ++i) {
      int row = wr * 64 + i * 16 + la;
      a[i] = *reinterpret_cast<const bf16x8*>(&As[buf][row * 32 + ((q ^ ((row >> 1) & 3)) << 3)]);
    }
#pragma unroll
    for (int j = 0; j < 4; ++j) {
      int row = wc * 64 + j * 16 + la;
      b[j] = *reinterpret_cast<const bf16x8*>(&Bs[buf][row * 32 + ((q ^ ((row >> 1) & 3)) << 3)]);
    }
    __builtin_amdgcn_s_setprio(1);
#pragma unroll
    for (int i = 0; i < 4; ++i)
#pragma unroll
      for (int j = 0; j < 4; ++j)
        acc[i][j] = __builtin_amdgcn_mfma_f32_16x16x32_bf16(a[i], b[j], acc[i][j], 0, 0, 0);
    __builtin_amdgcn_s_setprio(0);
  };

  stage(0, 0); stage(1, 1);             // 8 loads/thread in flight
  int cb = 0, sb = 2;
  for (int kt = 0; kt < 14; ++kt) {
    VMCNT(4);                           // tile kt landed; kt+1 flying
    __builtin_amdgcn_s_barrier();       // all waves' kt landed; buf sb free
    stage(sb, kt + 2);
    body(cb);
    cb = (cb == 2) ? 0 : cb + 1;
    sb = (sb == 2) ? 0 : sb + 1;
  }
  VMCNT(4); __builtin_amdgcn_s_barrier(); body(2);   // kt=14 -> buf 14%3=2
  VMCNT(0); __builtin_amdgcn_s_barrier(); body(0);   // kt=15 -> buf 0

  const int r0 = q * 4, cn = lane & 15;
  if (z < 2) {
    u16* out = (z == 0) ? Q : K;
#pragma unroll
    for (int i = 0; i < 4; ++i)
#pragma unroll
      for (int j = 0; j < 4; ++j)
#pragma unroll
        for (int r = 0; r < 4; ++r) {
          int m = bm + 64 * wr + 16 * i + r0 + r;
          int n = bn + 64 * wc + 16 * j + cn;
          out[(size_t)m * 512 + n] = f2bf(acc[i][j][r]);
        }
  } else {
#pragma unroll
    for (int i = 0; i < 4; ++i)
#pragma unroll
      for (int j = 0; j < 4; ++j)
#pragma unroll
        for (int r = 0; r < 4; ++r) {
          int m = bm + 64 * wr + 16 * i + r0 + r;
          int u = bn + 64 * wc + 16 * j + cn;
          int b = m >> 11, s = m & 2047;
          Vt[((size_t)b * 512 + u) * 2048 + s] = f2bf(acc[i][j][r]);
        }
  }
}

// ------ P = exp(Q K^T / sqrt(512)) -> bf16: 256x256, ring-4 (round-14) ------
__global__ __launch_bounds__(512) void scores8_kernel(const u16* __restrict__ Q,
                                                      const u16* __restrict__ K,
                                                      u16* __restrict__ S) {
  __shared__ u16 ring[4][2][256 * 32];  // [buf][A=0/B=1][256 rows][32 k]
  const int bb = blockIdx.x;            // batch -> XCD
  const int bm = blockIdx.y * 256;
  const int bn = blockIdx.z * 256;
  const u16* Aq = Q + (size_t)(bb * 2048 + bm) * 512;
  const u16* Bk = K + (size_t)(bb * 2048 + bn) * 512;

  const int t = threadIdx.x;
  const int lane = t & 63;
  const int wid = t >> 6;
  const int wm = wid >> 2, wn = wid & 3;
  const int la = lane & 15;
  const int q = lane >> 4;              // k-slot 0..3 (8 elems each)

  f32x4 acc[8][4] = {};

  auto stage = [&](int kt) {
    const int r = kt & 3;
    const int koff = kt * 32;
#pragma unroll
    for (int half = 0; half < 2; ++half) {
      int c = half * 512 + t;
      int row = c >> 2;
      int col = ((c & 3) ^ ((row >> 1) & 3)) << 3;   // inverse swizzle on source
      __builtin_amdgcn_global_load_lds(
          (const __attribute__((address_space(1))) void*)(Aq + (size_t)row * 512 + koff + col),
          (__attribute__((address_space(3))) void*)(&ring[r][0][c * 8]), 16, 0, 0);
      __builtin_amdgcn_global_load_lds(
          (const __attribute__((address_space(1))) void*)(Bk + (size_t)row * 512 + koff + col),
          (__attribute__((address_space(3))) void*)(&ring[r][1][c * 8]), 16, 0, 0);
    }
  };

  auto body = [&](int kt) {
    const int r = kt & 3;
    const u16* At = ring[r][0];
    const u16* Bt = ring[r][1];
    bf16x8 bfr[4], afr[8];
#pragma unroll
    for (int j = 0; j < 4; ++j) {
      int row = wn * 64 + j * 16 + la;
      bfr[j] = *reinterpret_cast<const bf16x8*>(Bt + row * 32 + ((q ^ ((row >> 1) & 3)) << 3));
    }
#pragma unroll
    for (int i = 0; i < 8; ++i) {
      int row = wm * 128 + i * 16 + la;
      afr[i] = *reinterpret_cast<const bf16x8*>(At + row * 32 + ((q ^ ((row >> 1) & 3)) << 3));
    }
    __builtin_amdgcn_s_setprio(1);
#pragma unroll
    for (int i = 0; i < 8; ++i)
#pragma unroll
      for (int j = 0; j < 4; ++j)
        acc[i][j] = __builtin_amdgcn_mfma_f32_16x16x32_bf16(afr[i], bfr[j], acc[i][j], 0, 0, 0);
    __builtin_amdgcn_s_setprio(0);
  };

  stage(0); stage(1); stage(2);         // 12 loads/thread in flight
  for (int kt = 0; kt < 13; ++kt) {
    VMCNT(8);                           // kt's 4 loads landed; kt+1/kt+2 fly
    __builtin_amdgcn_s_barrier();       // all waves' kt landed; buf[(kt+3)&3] free
    stage(kt + 3);
    body(kt);
  }
  VMCNT(8); __builtin_amdgcn_s_barrier(); body(13);
  VMCNT(4); __builtin_amdgcn_s_barrier(); body(14);
  VMCNT(0); __builtin_amdgcn_s_barrier(); body(15);

  u16* C = S + (size_t)bb * 2048 * 2048;
  const float scale = 0.06375872127f;   // log2(e)/sqrt(512)
  const int r0h = q * 4;
#pragma unroll
  for (int i = 0; i < 8; ++i)
#pragma unroll
    for (int j = 0; j < 4; ++j)
#pragma unroll
      for (int r = 0; r < 4; ++r) {
        int m = bm + wm * 128 + i * 16 + r0h + r;
        int n = bn + wn * 64 + j * 16 + la;
        C[(size_t)m * 2048 + n] = f2bf(fexp2(acc[i][j][r] * scale));
      }
}

// ---- out = (P * V) / rowsum(P): 128x128 tile, ring-4 counted-vmcnt ----
// Round-1 post-mortem: direct global->reg lost the pipeline (compiler sank
// loads, VGPR=112 proves it; MfmaUtil 10.7%). Reverted to the proven LDS
// global_load_lds pipeline and DEEPENED it: ring-4, 3 tiles prefetched,
// VMCNT(8) (2 full tiles flying at the wait) — the exact schedule proven
// in scores8_kernel. LDS 64.5 KB -> still 2 blocks/CU (grid caps at 2).
__global__ __launch_bounds__(256) void pv_kernel(const u16* __restrict__ S,
                                                 const u16* __restrict__ Vt,
                                                 float* __restrict__ out) {
  __shared__ u16 As[4][128 * 32], Bs[4][128 * 32];
  __shared__ float larr[128];
  const int id = blockIdx.x;
  const int b = id & 7;                   // batch == XCD
  const int local = id >> 3;              // 0..63
  const int bn = (local & 3) * 128;       // u cols
  const int bm = (local >> 2) * 128;      // q rows

  const u16* A = S + (size_t)(b * 2048 + bm) * 2048;
  const u16* Bt = Vt + ((size_t)b * 512 + bn) * 2048;

  const int t = threadIdx.x;
  const int lane = t & 63;
  const int w = t >> 6;
  const int wr = w >> 1, wc = w & 1;
  const int la = lane & 15;
  const int q = lane >> 4;
  f32x4 acc[4][4] = {};
  float lacc[4] = {0.f, 0.f, 0.f, 0.f};

  auto stage = [&](int kt) {
    const int buf = kt & 3;
    const int k0 = kt * 32;
#pragma unroll
    for (int it = 0; it < 2; ++it) {    // A (P rows): 128 rows -> 512 chunks
      int c = it * 256 + t, row = c >> 2;
      int col = ((c & 3) ^ ((row >> 1) & 3)) << 3;
      __builtin_amdgcn_global_load_lds(
          (const __attribute__((address_space(1))) void*)(A + (size_t)row * 2048 + k0 + col),
          (__attribute__((address_space(3))) void*)(&As[buf][c * 8]), 16, 0, 0);
    }
#pragma unroll
    for (int it = 0; it < 2; ++it) {    // B (Vt rows): 128 rows -> 512 chunks
      int c = it * 256 + t, row = c >> 2;
      int col = ((c & 3) ^ ((row >> 1) & 3)) << 3;
      __builtin_amdgcn_global_load_lds(
          (const __attribute__((address_space(1))) void*)(Bt + (size_t)row * 2048 + k0 + col),
          (__attribute__((address_space(3))) void*)(&Bs[buf][c * 8]), 16, 0, 0);
    }
  };

  auto body = [&](int kt) {
    const int buf = kt & 3;
    bf16x8 a[4], bb[4];
#pragma unroll
    for (int i = 0; i < 4; ++i) {
      int row = wr * 64 + i * 16 + la;
      a[i] = *reinterpret_cast<const bf16x8*>(&As[buf][row * 32 + ((q ^ ((row >> 1) & 3)) << 3)]);
    }
    if (wc == 0) {                      // count each P element exactly once
#pragma unroll
      for (int i = 0; i < 4; ++i) {
        float ls = 0.f;
#pragma unroll
        for (int e = 0; e < 8; ++e) ls += (float)a[i][e];
        lacc[i] += ls;
      }
    }
#pragma unroll
    for (int j = 0; j < 4; ++j) {
      int row = wc * 64 + j * 16 + la;
      bb[j] = *reinterpret_cast<const bf16x8*>(&Bs[buf][row * 32 + ((q ^ ((row >> 1) & 3)) << 3)]);
    }
    __builtin_amdgcn_s_setprio(1);
#pragma unroll
    for (int i = 0; i < 4; ++i)
#pragma unroll
      for (int j = 0; j < 4; ++j)
        acc[i][j] = __builtin_amdgcn_mfma_f32_16x16x32_bf16(a[i], bb[j], acc[i][j], 0, 0, 0);
    __builtin_amdgcn_s_setprio(0);
  };

  stage(0); stage(1); stage(2);         // 12 loads/thread in flight
  for (int kt = 0; kt < 61; ++kt) {
    VMCNT(8);                           // tile kt landed; kt+1/kt+2 flying
    __builtin_amdgcn_s_barrier();       // all waves' kt landed; buf[(kt+3)&3] free
    stage(kt + 3);
    body(kt);
  }
  VMCNT(8); __builtin_amdgcn_s_barrier(); body(61);
  VMCNT(4); __builtin_amdgcn_s_barrier(); body(62);
  VMCNT(0); __builtin_amdgcn_s_barrier(); body(63);

  // ---- epilogue: reduce row partials over q-lanes, normalize, store ---
  float l[4];
#pragma unroll
  for (int i = 0; i < 4; ++i) {
    l[i] = lacc[i];
    l[i] += __shfl_xor(l[i], 16);
    l[i] += __shfl_xor(l[i], 32);       // sum across 4 q-lanes (la preserved)
  }
  if (wc == 0 && q == 0) {              // one writer per row: 2 wr x 16 la x 4 i
#pragma unroll
    for (int i = 0; i < 4; ++i) larr[wr * 64 + i * 16 + la] = l[i];
  }
  __syncthreads();

  float* C = out + ((size_t)b * 2048 + bm) * 512;
  const int r0 = q * 4, cn = lane & 15;
  float inv[4][4];
#pragma unroll
  for (int i = 0; i < 4; ++i)
#pragma unroll
    for (int r = 0; r < 4; ++r)
      inv[i][r] = 1.0f / larr[wr * 64 + i * 16 + r0 + r];
#pragma unroll
  for (int i = 0; i < 4; ++i)
#pragma unroll
    for (int j = 0; j < 4; ++j)
#pragma unroll
      for (int r = 0; r < 4; ++r) {
        int m = 64 * wr + 16 * i + r0 + r;
        int n = bn + 64 * wc + 16 * j + cn;
        C[(size_t)m * 512 + n] = acc[i][j][r] * inv[i][r];
      }
}

extern "C" void kernel_launch(void* const* d_in, const int* in_sizes, int n_in,
                              void* d_out, int out_size, void* d_ws, size_t ws_size,
                              hipStream_t stream) {
  const float* x  = (const float*)d_in[0];
  const float* Wq = (const float*)d_in[1];
  const float* Wk = (const float*)d_in[2];
  const float* Wv = (const float*)d_in[3];
  float* out = (float*)d_out;

  // ws layout: Xb bf16[16384][512] | Wt bf16[3][512][512] | Q | K | Vt | S bf16[8][2048][2048]
  char* p = (char*)d_ws;
  u16* Xb = (u16*)p;            p += (size_t)16384 * 512 * 2;
  u16* Wt = (u16*)p;            p += (size_t)3 * 512 * 512 * 2;
  u16* Q  = (u16*)p;            p += (size_t)16384 * 512 * 2;
  u16* K  = (u16*)p;            p += (size_t)16384 * 512 * 2;
  u16* Vt = (u16*)p;            p += (size_t)16384 * 512 * 2;
  u16* S  = (u16*)p;

  cast_x_kernel<<<dim3(8192), dim3(256), 0, stream>>>(x, Xb, 16384 * 512 / 4);
  transpose_w_kernel<<<dim3(16, 16, 3), dim3(32, 32), 0, stream>>>(Wq, Wk, Wv, Wt);
  qkv_kernel<<<dim3(4, 128, 3), dim3(256), 0, stream>>>(Xb, Wt, Q, K, Vt);
  scores8_kernel<<<dim3(8, 8, 8), dim3(512), 0, stream>>>(Q, K, S);
  pv_kernel<<<dim3(512), dim3(256), 0, stream>>>(S, Vt, out);
}

// Round 3
// 149.935 us; speedup vs baseline: 1.4461x; 1.0259x over previous
//
#include <hip/hip_runtime.h>

typedef __attribute__((ext_vector_type(8))) __bf16 bf16x8;
typedef __attribute__((ext_vector_type(4))) float f32x4;
typedef unsigned short u16;
typedef unsigned int u32;

#define VMCNT(n) asm volatile("s_waitcnt vmcnt(" #n ")" ::: "memory")

__device__ __forceinline__ u16 f2bf(float f) {
  union { float f; u32 u; } v; v.f = f;
  u32 r = v.u + 0x7FFFu + ((v.u >> 16) & 1u);
  return (u16)(r >> 16);
}
__device__ __forceinline__ float fexp2(float x) {  // 2^x via v_exp_f32
  float r; asm("v_exp_f32 %0, %1" : "=v"(r) : "v"(x)); return r;
}

// ---------------- cast x fp32 -> bf16 (4 elems/thread) ----------------
__global__ __launch_bounds__(256) void cast_x_kernel(const float* __restrict__ x,
                                                     u16* __restrict__ xb, int n4) {
  int i = blockIdx.x * 256 + threadIdx.x;
  if (i >= n4) return;
  float4 v = reinterpret_cast<const float4*>(x)[i];
  ushort4 o;
  o.x = f2bf(v.x); o.y = f2bf(v.y); o.z = f2bf(v.z); o.w = f2bf(v.w);
  reinterpret_cast<ushort4*>(xb)[i] = o;
}

// ------- transpose weights: Wt[u][d] = W[d][u], fp32 -> bf16 ----------
__global__ __launch_bounds__(1024) void transpose_w_kernel(const float* __restrict__ Wq,
                                                           const float* __restrict__ Wk,
                                                           const float* __restrict__ Wv,
                                                           u16* __restrict__ Wt) {
  const float* src = blockIdx.z == 0 ? Wq : (blockIdx.z == 1 ? Wk : Wv);
  u16* dst = Wt + (size_t)blockIdx.z * 512 * 512;
  __shared__ float tile[32][33];
  int u0 = blockIdx.x * 32, d0 = blockIdx.y * 32;
  tile[threadIdx.y][threadIdx.x] = src[(d0 + threadIdx.y) * 512 + u0 + threadIdx.x];
  __syncthreads();
  dst[(u0 + threadIdx.y) * 512 + d0 + threadIdx.x] = f2bf(tile[threadIdx.x][threadIdx.y]);
}

// ---------------- QKV projection: 128x128 tile, ring-3 counted-vmcnt ----
// z==2 (V) now writes Vt2[b][kt][u][32] (kt = s>>5): pv stages contiguous
// 8KB tiles instead of 64B-at-4KB-stride gathers.
__global__ __launch_bounds__(256) void qkv_kernel(const u16* __restrict__ Xb,
                                                  const u16* __restrict__ Wt3,
                                                  u16* __restrict__ Q, u16* __restrict__ K,
                                                  u16* __restrict__ Vt2) {
  __shared__ u16 As[3][128 * 32], Bs[3][128 * 32];
  const int bm = blockIdx.y * 128;
  const int bn = blockIdx.x * 128;
  const int z = blockIdx.z;
  const u16* A = Xb + (size_t)bm * 512;
  const u16* Bt = Wt3 + (size_t)z * 512 * 512 + (size_t)bn * 512;

  const int t = threadIdx.x;
  const int lane = t & 63;
  const int w = t >> 6;
  const int wr = w >> 1, wc = w & 1;
  const int la = lane & 15;
  const int q = lane >> 4;
  f32x4 acc[4][4] = {};

  auto stage = [&](int buf, int kt) {
    const int k0 = kt * 32;
#pragma unroll
    for (int it = 0; it < 2; ++it) {    // A: 128 rows -> 512 chunks
      int c = it * 256 + t, row = c >> 2;
      int col = ((c & 3) ^ ((row >> 1) & 3)) << 3;
      __builtin_amdgcn_global_load_lds(
          (const __attribute__((address_space(1))) void*)(A + (size_t)row * 512 + k0 + col),
          (__attribute__((address_space(3))) void*)(&As[buf][c * 8]), 16, 0, 0);
    }
#pragma unroll
    for (int it = 0; it < 2; ++it) {    // B: 128 rows -> 512 chunks
      int c = it * 256 + t, row = c >> 2;
      int col = ((c & 3) ^ ((row >> 1) & 3)) << 3;
      __builtin_amdgcn_global_load_lds(
          (const __attribute__((address_space(1))) void*)(Bt + (size_t)row * 512 + k0 + col),
          (__attribute__((address_space(3))) void*)(&Bs[buf][c * 8]), 16, 0, 0);
    }
  };

  auto body = [&](int buf) {
    bf16x8 a[4], b[4];
#pragma unroll
    for (int i = 0; i < 4; ++i) {
      int row = wr * 64 + i * 16 + la;
      a[i] = *reinterpret_cast<const bf16x8*>(&As[buf][row * 32 + ((q ^ ((row >> 1) & 3)) << 3)]);
    }
#pragma unroll
    for (int j = 0; j < 4; ++j) {
      int row = wc * 64 + j * 16 + la;
      b[j] = *reinterpret_cast<const bf16x8*>(&Bs[buf][row * 32 + ((q ^ ((row >> 1) & 3)) << 3)]);
    }
    __builtin_amdgcn_s_setprio(1);
#pragma unroll
    for (int i = 0; i < 4; ++i)
#pragma unroll
      for (int j = 0; j < 4; ++j)
        acc[i][j] = __builtin_amdgcn_mfma_f32_16x16x32_bf16(a[i], b[j], acc[i][j], 0, 0, 0);
    __builtin_amdgcn_s_setprio(0);
  };

  stage(0, 0); stage(1, 1);             // 8 loads/thread in flight
  int cb = 0, sb = 2;
  for (int kt = 0; kt < 14; ++kt) {
    VMCNT(4);                           // tile kt landed; kt+1 flying
    __builtin_amdgcn_s_barrier();       // all waves' kt landed; buf sb free
    stage(sb, kt + 2);
    body(cb);
    cb = (cb == 2) ? 0 : cb + 1;
    sb = (sb == 2) ? 0 : sb + 1;
  }
  VMCNT(4); __builtin_amdgcn_s_barrier(); body(2);   // kt=14 -> buf 14%3=2
  VMCNT(0); __builtin_amdgcn_s_barrier(); body(0);   // kt=15 -> buf 0

  const int r0 = q * 4, cn = lane & 15;
  if (z < 2) {
    u16* out = (z == 0) ? Q : K;
#pragma unroll
    for (int i = 0; i < 4; ++i)
#pragma unroll
      for (int j = 0; j < 4; ++j)
#pragma unroll
        for (int r = 0; r < 4; ++r) {
          int m = bm + 64 * wr + 16 * i + r0 + r;
          int n = bn + 64 * wc + 16 * j + cn;
          out[(size_t)m * 512 + n] = f2bf(acc[i][j][r]);
        }
  } else {
#pragma unroll
    for (int i = 0; i < 4; ++i)
#pragma unroll
      for (int j = 0; j < 4; ++j)
#pragma unroll
        for (int r = 0; r < 4; ++r) {
          int m = bm + 64 * wr + 16 * i + r0 + r;
          int u = bn + 64 * wc + 16 * j + cn;
          int b = m >> 11, s = m & 2047;
          // Vt2[b][kt=s>>5][u][s&31]
          Vt2[(((size_t)b * 64 + (s >> 5)) * 512 + u) * 32 + (s & 31)] = f2bf(acc[i][j][r]);
        }
  }
}

// ------ P = exp(Q K^T / sqrt(512)) -> bf16: 256x256, ring-4 ------
// Output layout now S2[b][kt][q][32] (kt = k>>5): pv stages contiguous
// 8KB tiles. Write-side coalescing unchanged (32B runs per 16 lanes).
__global__ __launch_bounds__(512) void scores8_kernel(const u16* __restrict__ Q,
                                                      const u16* __restrict__ K,
                                                      u16* __restrict__ S2) {
  __shared__ u16 ring[4][2][256 * 32];  // [buf][A=0/B=1][256 rows][32 k]
  const int bb = blockIdx.x;            // batch -> XCD
  const int bm = blockIdx.y * 256;
  const int bn = blockIdx.z * 256;
  const u16* Aq = Q + (size_t)(bb * 2048 + bm) * 512;
  const u16* Bk = K + (size_t)(bb * 2048 + bn) * 512;

  const int t = threadIdx.x;
  const int lane = t & 63;
  const int wid = t >> 6;
  const int wm = wid >> 2, wn = wid & 3;
  const int la = lane & 15;
  const int q = lane >> 4;              // k-slot 0..3 (8 elems each)

  f32x4 acc[8][4] = {};

  auto stage = [&](int kt) {
    const int r = kt & 3;
    const int koff = kt * 32;
#pragma unroll
    for (int half = 0; half < 2; ++half) {
      int c = half * 512 + t;
      int row = c >> 2;
      int col = ((c & 3) ^ ((row >> 1) & 3)) << 3;   // inverse swizzle on source
      __builtin_amdgcn_global_load_lds(
          (const __attribute__((address_space(1))) void*)(Aq + (size_t)row * 512 + koff + col),
          (__attribute__((address_space(3))) void*)(&ring[r][0][c * 8]), 16, 0, 0);
      __builtin_amdgcn_global_load_lds(
          (const __attribute__((address_space(1))) void*)(Bk + (size_t)row * 512 + koff + col),
          (__attribute__((address_space(3))) void*)(&ring[r][1][c * 8]), 16, 0, 0);
    }
  };

  auto body = [&](int kt) {
    const int r = kt & 3;
    const u16* At = ring[r][0];
    const u16* Bt = ring[r][1];
    bf16x8 bfr[4], afr[8];
#pragma unroll
    for (int j = 0; j < 4; ++j) {
      int row = wn * 64 + j * 16 + la;
      bfr[j] = *reinterpret_cast<const bf16x8*>(Bt + row * 32 + ((q ^ ((row >> 1) & 3)) << 3));
    }
#pragma unroll
    for (int i = 0; i < 8; ++i) {
      int row = wm * 128 + i * 16 + la;
      afr[i] = *reinterpret_cast<const bf16x8*>(At + row * 32 + ((q ^ ((row >> 1) & 3)) << 3));
    }
    __builtin_amdgcn_s_setprio(1);
#pragma unroll
    for (int i = 0; i < 8; ++i)
#pragma unroll
      for (int j = 0; j < 4; ++j)
        acc[i][j] = __builtin_amdgcn_mfma_f32_16x16x32_bf16(afr[i], bfr[j], acc[i][j], 0, 0, 0);
    __builtin_amdgcn_s_setprio(0);
  };

  stage(0); stage(1); stage(2);         // 12 loads/thread in flight
  for (int kt = 0; kt < 13; ++kt) {
    VMCNT(8);                           // kt's 4 loads landed; kt+1/kt+2 fly
    __builtin_amdgcn_s_barrier();       // all waves' kt landed; buf[(kt+3)&3] free
    stage(kt + 3);
    body(kt);
  }
  VMCNT(8); __builtin_amdgcn_s_barrier(); body(13);
  VMCNT(4); __builtin_amdgcn_s_barrier(); body(14);
  VMCNT(0); __builtin_amdgcn_s_barrier(); body(15);

  const float scale = 0.06375872127f;   // log2(e)/sqrt(512)
  const int r0h = q * 4;
#pragma unroll
  for (int i = 0; i < 8; ++i)
#pragma unroll
    for (int j = 0; j < 4; ++j) {
      int n = bn + wn * 64 + j * 16;                 // k-col base (la added below)
      int kt_j = n >> 5;
      int ke_j = (n & 31) + la;                      // no carry: (n&31) in {0,16}, la<16
      u16* dst = S2 + ((size_t)(bb * 64 + kt_j) * 2048) * 32 + ke_j;
#pragma unroll
      for (int r = 0; r < 4; ++r) {
        int m = bm + wm * 128 + i * 16 + r0h + r;
        dst[(size_t)m * 32] = f2bf(fexp2(acc[i][j][r] * scale));
      }
    }
}

// ---- out = (P * V) / rowsum(P): 128x128 tile, ring-4 counted-vmcnt ----
// Round-2 post-mortem: depth-insensitive at 62us -> staging was txn-RATE
// bound (16x 64B@4KB-stride txns per wave-instr). Fix: S2/Vt2 tiled
// layouts make each 8KB staged tile fully contiguous (sequential 64B
// lines). LDS contents byte-identical; only global source addressing
// changed. ds_read/MFMA/epilogue untouched.
__global__ __launch_bounds__(256) void pv_kernel(const u16* __restrict__ S2,
                                                 const u16* __restrict__ Vt2,
                                                 float* __restrict__ out) {
  __shared__ u16 As[4][128 * 32], Bs[4][128 * 32];
  __shared__ float larr[128];
  const int id = blockIdx.x;
  const int b = id & 7;                   // batch == XCD
  const int local = id >> 3;              // 0..63
  const int bn = (local & 3) * 128;       // u cols
  const int bm = (local >> 2) * 128;      // q rows

  // S2[b][kt][q][32]: tile base for (b,kt,bm) = A2 + kt*65536 (+row*32+ke)
  const u16* A2 = S2 + ((size_t)b * 64 * 2048 + (size_t)bm) * 32;
  // Vt2[b][kt][u][32]: tile base for (b,kt,bn) = B2 + kt*16384 (+row*32+ke)
  const u16* B2 = Vt2 + ((size_t)b * 64 * 512 + (size_t)bn) * 32;

  const int t = threadIdx.x;
  const int lane = t & 63;
  const int w = t >> 6;
  const int wr = w >> 1, wc = w & 1;
  const int la = lane & 15;
  const int q = lane >> 4;
  f32x4 acc[4][4] = {};
  float lacc[4] = {0.f, 0.f, 0.f, 0.f};

  auto stage = [&](int kt) {
    const int buf = kt & 3;
    const u16* At = A2 + (size_t)kt * 65536;   // 2048*32
    const u16* Bt = B2 + (size_t)kt * 16384;   // 512*32
#pragma unroll
    for (int it = 0; it < 2; ++it) {    // A (P rows): 128 rows -> 512 chunks
      int c = it * 256 + t, row = c >> 2;
      int col = ((c & 3) ^ ((row >> 1) & 3)) << 3;
      __builtin_amdgcn_global_load_lds(
          (const __attribute__((address_space(1))) void*)(At + row * 32 + col),
          (__attribute__((address_space(3))) void*)(&As[buf][c * 8]), 16, 0, 0);
    }
#pragma unroll
    for (int it = 0; it < 2; ++it) {    // B (Vt rows): 128 rows -> 512 chunks
      int c = it * 256 + t, row = c >> 2;
      int col = ((c & 3) ^ ((row >> 1) & 3)) << 3;
      __builtin_amdgcn_global_load_lds(
          (const __attribute__((address_space(1))) void*)(Bt + row * 32 + col),
          (__attribute__((address_space(3))) void*)(&Bs[buf][c * 8]), 16, 0, 0);
    }
  };

  auto body = [&](int kt) {
    const int buf = kt & 3;
    bf16x8 a[4], bb[4];
#pragma unroll
    for (int i = 0; i < 4; ++i) {
      int row = wr * 64 + i * 16 + la;
      a[i] = *reinterpret_cast<const bf16x8*>(&As[buf][row * 32 + ((q ^ ((row >> 1) & 3)) << 3)]);
    }
    if (wc == 0) {                      // count each P element exactly once
#pragma unroll
      for (int i = 0; i < 4; ++i) {
        float ls = 0.f;
#pragma unroll
        for (int e = 0; e < 8; ++e) ls += (float)a[i][e];
        lacc[i] += ls;
      }
    }
#pragma unroll
    for (int j = 0; j < 4; ++j) {
      int row = wc * 64 + j * 16 + la;
      bb[j] = *reinterpret_cast<const bf16x8*>(&Bs[buf][row * 32 + ((q ^ ((row >> 1) & 3)) << 3)]);
    }
    __builtin_amdgcn_s_setprio(1);
#pragma unroll
    for (int i = 0; i < 4; ++i)
#pragma unroll
      for (int j = 0; j < 4; ++j)
        acc[i][j] = __builtin_amdgcn_mfma_f32_16x16x32_bf16(a[i], bb[j], acc[i][j], 0, 0, 0);
    __builtin_amdgcn_s_setprio(0);
  };

  stage(0); stage(1); stage(2);         // 12 loads/thread in flight
  for (int kt = 0; kt < 61; ++kt) {
    VMCNT(8);                           // tile kt landed; kt+1/kt+2 flying
    __builtin_amdgcn_s_barrier();       // all waves' kt landed; buf[(kt+3)&3] free
    stage(kt + 3);
    body(kt);
  }
  VMCNT(8); __builtin_amdgcn_s_barrier(); body(61);
  VMCNT(4); __builtin_amdgcn_s_barrier(); body(62);
  VMCNT(0); __builtin_amdgcn_s_barrier(); body(63);

  // ---- epilogue: reduce row partials over q-lanes, normalize, store ---
  float l[4];
#pragma unroll
  for (int i = 0; i < 4; ++i) {
    l[i] = lacc[i];
    l[i] += __shfl_xor(l[i], 16);
    l[i] += __shfl_xor(l[i], 32);       // sum across 4 q-lanes (la preserved)
  }
  if (wc == 0 && q == 0) {              // one writer per row: 2 wr x 16 la x 4 i
#pragma unroll
    for (int i = 0; i < 4; ++i) larr[wr * 64 + i * 16 + la] = l[i];
  }
  __syncthreads();

  float* C = out + ((size_t)b * 2048 + bm) * 512;
  const int r0 = q * 4, cn = lane & 15;
  float inv[4][4];
#pragma unroll
  for (int i = 0; i < 4; ++i)
#pragma unroll
    for (int r = 0; r < 4; ++r)
      inv[i][r] = 1.0f / larr[wr * 64 + i * 16 + r0 + r];
#pragma unroll
  for (int i = 0; i < 4; ++i)
#pragma unroll
    for (int j = 0; j < 4; ++j)
#pragma unroll
      for (int r = 0; r < 4; ++r) {
        int m = 64 * wr + 16 * i + r0 + r;
        int n = bn + 64 * wc + 16 * j + cn;
        C[(size_t)m * 512 + n] = acc[i][j][r] * inv[i][r];
      }
}

extern "C" void kernel_launch(void* const* d_in, const int* in_sizes, int n_in,
                              void* d_out, int out_size, void* d_ws, size_t ws_size,
                              hipStream_t stream) {
  const float* x  = (const float*)d_in[0];
  const float* Wq = (const float*)d_in[1];
  const float* Wk = (const float*)d_in[2];
  const float* Wv = (const float*)d_in[3];
  float* out = (float*)d_out;

  // ws layout: Xb bf16[16384][512] | Wt bf16[3][512][512] | Q | K | Vt2 | S2
  char* p = (char*)d_ws;
  u16* Xb = (u16*)p;            p += (size_t)16384 * 512 * 2;
  u16* Wt = (u16*)p;            p += (size_t)3 * 512 * 512 * 2;
  u16* Q  = (u16*)p;            p += (size_t)16384 * 512 * 2;
  u16* K  = (u16*)p;            p += (size_t)16384 * 512 * 2;
  u16* Vt2 = (u16*)p;           p += (size_t)16384 * 512 * 2;
  u16* S2 = (u16*)p;

  cast_x_kernel<<<dim3(8192), dim3(256), 0, stream>>>(x, Xb, 16384 * 512 / 4);
  transpose_w_kernel<<<dim3(16, 16, 3), dim3(32, 32), 0, stream>>>(Wq, Wk, Wv, Wt);
  qkv_kernel<<<dim3(4, 128, 3), dim3(256), 0, stream>>>(Xb, Wt, Q, K, Vt2);
  scores8_kernel<<<dim3(8, 8, 8), dim3(512), 0, stream>>>(Q, K, S2);
  pv_kernel<<<dim3(512), dim3(256), 0, stream>>>(S2, Vt2, out);
}